// Round 6
// baseline (212.493 us; speedup 1.0000x reference)
//
#include <hip/hip_runtime.h>

typedef unsigned short ushort_t;
typedef __bf16 bf16x8 __attribute__((ext_vector_type(8)));
typedef float f32x4 __attribute__((ext_vector_type(4)));
typedef float f32x16 __attribute__((ext_vector_type(16)));
typedef unsigned short u16x8 __attribute__((ext_vector_type(8)));
typedef unsigned int u32x2 __attribute__((ext_vector_type(2)));
typedef unsigned int u32x4 __attribute__((ext_vector_type(4)));

#define MFMA16(a, b, c) __builtin_amdgcn_mfma_f32_16x16x32_bf16((a), (b), (c), 0, 0, 0)
#define MFMA32(a, b, c) __builtin_amdgcn_mfma_f32_32x32x16_bf16((a), (b), (c), 0, 0, 0)

// ---------- constants ----------
// B=8, N=1024, C=768, H=12, hd=64
#define SEQ 1024
#define NHEAD 12
#define HD 64
#define CDIM 768
#define TS 6291456      // per-tensor stride in qkv buf: 96*1024*64
#define QSCALE 0.1803368801111204f   // 0.125 * log2(e)

// ---------- helpers ----------
__device__ __forceinline__ ushort_t f2bf(float f) {
  __bf16 b = (__bf16)f;                       // HW cvt (RNE) on gfx950
  return __builtin_bit_cast(ushort_t, b);
}
__device__ __forceinline__ unsigned pk2(float lo, float hi) {
  return (unsigned)f2bf(lo) | ((unsigned)f2bf(hi) << 16);
}

// permlane32_swap: dst.row1 <-> src.row0. Returns {a.lo|b.lo, a.hi|b.hi}.
__device__ __forceinline__ void plswap(unsigned &a, unsigned &b) {
  u32x2 r = __builtin_amdgcn_permlane32_swap(a, b, false, false);
  a = r[0];
  b = r[1];
}

typedef __attribute__((address_space(1))) void gvoid_t;
typedef __attribute__((address_space(3))) void lvoid_t;
__device__ __forceinline__ void async16(const ushort_t* g, ushort_t* l) {
  __builtin_amdgcn_global_load_lds((gvoid_t*)g, (lvoid_t*)l, 16, 0, 0);
}

// ---------- fused prep: convert x, transpose weights, rope table ----------
__device__ __forceinline__ void transpose_body(const float* __restrict__ in,
                                               ushort_t* __restrict__ out,
                                               int R, int C, int bxi, int byi,
                                               float (*tile)[33]) {
  int bx = bxi * 32, by = byi * 32;
  int tx = threadIdx.x & 31, ty = threadIdx.x >> 5;  // 32 x 8
#pragma unroll
  for (int i = ty; i < 32; i += 8) {
    int r = by + i, c = bx + tx;
    if (r < R && c < C) tile[i][tx] = in[(size_t)r * C + c];
  }
  __syncthreads();
#pragma unroll
  for (int i = ty; i < 32; i += 8) {
    int r = bx + i, c = by + tx;
    if (r < C && c < R) out[(size_t)r * R + c] = f2bf(tile[tx][i]);
  }
}

__global__ void __launch_bounds__(256) prep_all(const float* __restrict__ x,
                                                const float* __restrict__ w_qkv,
                                                const float* __restrict__ w_proj,
                                                ushort_t* __restrict__ xb,
                                                ushort_t* __restrict__ wqkvT,
                                                ushort_t* __restrict__ wprojT,
                                                float* __restrict__ tab) {
  __shared__ float tile[32][33];
  const int bid = blockIdx.x;
  if (bid < 3072) {                       // x fp32 -> bf16
    int i = (bid * 256 + threadIdx.x) * 8;
    float4 a = *(const float4*)(x + i);
    float4 b = *(const float4*)(x + i + 4);
    u16x8 r;
    r[0] = f2bf(a.x); r[1] = f2bf(a.y); r[2] = f2bf(a.z); r[3] = f2bf(a.w);
    r[4] = f2bf(b.x); r[5] = f2bf(b.y); r[6] = f2bf(b.z); r[7] = f2bf(b.w);
    *(u16x8*)(xb + i) = r;
  } else if (bid < 3072 + 1728) {         // w_qkv (768x2304) -> wqkvT (2304x768)
    int t = bid - 3072;
    transpose_body(w_qkv, wqkvT, 768, 2304, t % 72, t / 72, tile);
  } else if (bid < 3072 + 1728 + 576) {   // w_proj (768x768) -> wprojT
    int t = bid - (3072 + 1728);
    transpose_body(w_proj, wprojT, 768, 768, t % 24, t / 24, tile);
  } else {                                // rope cos/sin table (fp64, matches numpy)
    int g = (bid - 5376) * 256 + threadIdx.x;   // 1024*32
    int n = g >> 5, j = g & 31;
    double invf = pow(10000.0, -((double)(2 * j)) / 64.0);
    double fr = (double)n * invf;
    tab[g * 2]     = (float)cos(fr);
    tab[g * 2 + 1] = (float)sin(fr);
  }
}

// ---------- GEMM core: C[128x128] = A[128x768] * Bt[128x768]^T ----------
// 32-wide K steps, TRIPLE-buffered LDS, counted vmcnt; bank-conflict-free
// chunk swizzle applied both-sides (pre-swizzled global src + swizzled read).
__device__ __forceinline__ void gemm_compute32(const ushort_t* la, const ushort_t* lb,
                                               int wm, int wn, int fr, int fq,
                                               f32x4 acc[4][4]) {
  bf16x8 aF[4], bF[4];
#pragma unroll
  for (int i = 0; i < 4; ++i) {
    const int R = wm + i * 16 + fr;
    aF[i] = *(const bf16x8*)(la + R * 32 + (((fq + (R >> 1)) & 3) << 3));
  }
#pragma unroll
  for (int j = 0; j < 4; ++j) {
    const int S = wn + j * 16 + fr;
    bF[j] = *(const bf16x8*)(lb + S * 32 + (((fq + (S >> 1)) & 3) << 3));
  }
#pragma unroll
  for (int i = 0; i < 4; ++i)
#pragma unroll
    for (int j = 0; j < 4; ++j) acc[i][j] = MFMA16(aF[i], bF[j], acc[i][j]);
}

__device__ __forceinline__ void gemm_bt_core(const ushort_t* __restrict__ A,
                                             const ushort_t* __restrict__ Bt,
                                             int bm, int bn,
                                             ushort_t (*ldsA)[4096],
                                             ushort_t (*ldsB)[4096],
                                             f32x4 acc[4][4]) {
  const int tid = threadIdx.x;
  const int lane = tid & 63, wid = tid >> 6;
  const int wm = (wid >> 1) * 64, wn = (wid & 1) * 64;
  const int fr = lane & 15, fq = lane >> 4;
#pragma unroll
  for (int i = 0; i < 4; ++i)
#pragma unroll
    for (int j = 0; j < 4; ++j) acc[i][j] = (f32x4){0.f, 0.f, 0.f, 0.f};

  const int srow = tid >> 2;                                  // 0..63
  const int scol = (((tid & 3) - (srow >> 1)) & 3) << 3;      // swizzled src chunk
  const ushort_t* aSrc = A + (size_t)(bm + srow) * CDIM + scol;
  const ushort_t* bSrc = Bt + (size_t)(bn + srow) * CDIM + scol;

#define STAGE_STEP(buf, s)                                                       \
  {                                                                              \
    async16(aSrc + (s) * 32, ldsA[buf] + tid * 8);                               \
    async16(aSrc + (size_t)64 * CDIM + (s) * 32, ldsA[buf] + 2048 + tid * 8);    \
    async16(bSrc + (s) * 32, ldsB[buf] + tid * 8);                               \
    async16(bSrc + (size_t)64 * CDIM + (s) * 32, ldsB[buf] + 2048 + tid * 8);    \
  }

  STAGE_STEP(0, 0);
  STAGE_STEP(1, 1);
  STAGE_STEP(2, 2);

#pragma unroll 3
  for (int s = 0; s < 21; ++s) {
    const int b = s % 3;
    asm volatile("s_waitcnt vmcnt(8)" ::: "memory");
    __builtin_amdgcn_sched_barrier(0);
    __builtin_amdgcn_s_barrier();
    __builtin_amdgcn_sched_barrier(0);
    gemm_compute32(ldsA[b], ldsB[b], wm, wn, fr, fq, acc);
    __builtin_amdgcn_sched_barrier(0);
    __builtin_amdgcn_s_barrier();
    __builtin_amdgcn_sched_barrier(0);
    STAGE_STEP(b, s + 3);
  }
  asm volatile("s_waitcnt vmcnt(8)" ::: "memory");
  __builtin_amdgcn_sched_barrier(0);
  __builtin_amdgcn_s_barrier();
  __builtin_amdgcn_sched_barrier(0);
  gemm_compute32(ldsA[0], ldsB[0], wm, wn, fr, fq, acc);
  asm volatile("s_waitcnt vmcnt(4)" ::: "memory");
  __builtin_amdgcn_sched_barrier(0);
  __builtin_amdgcn_s_barrier();
  __builtin_amdgcn_sched_barrier(0);
  gemm_compute32(ldsA[1], ldsB[1], wm, wn, fr, fq, acc);
  asm volatile("s_waitcnt vmcnt(0)" ::: "memory");
  __builtin_amdgcn_sched_barrier(0);
  __builtin_amdgcn_s_barrier();
  __builtin_amdgcn_sched_barrier(0);
  gemm_compute32(ldsA[2], ldsB[2], wm, wn, fr, fq, acc);
#undef STAGE_STEP
}

// GEMM1: qkv = x @ w_qkv^T with fused RoPE / V-transpose epilogue. (128^2 core)
__global__ void __launch_bounds__(256) gemm_qkv(const ushort_t* __restrict__ A,
                                                const ushort_t* __restrict__ Bt,
                                                const float* __restrict__ tab,
                                                ushort_t* __restrict__ qkv) {
  __shared__ __attribute__((aligned(16))) ushort_t ldsA[3][4096];
  __shared__ __attribute__((aligned(16))) ushort_t ldsB[3][4096];
  f32x4 acc[4][4];
  const int f = blockIdx.x;
  const int xcd = f & 7, r = f >> 3;          // r: 0..143
  const int bm = (xcd * 8 + (r & 7)) * 128;   // 64 bm tiles, 8 per XCD
  const int bn = (r >> 3) * 128;              // 18 bn tiles
  gemm_bt_core(A, Bt, bm, bn, ldsA, ldsB, acc);
  const int lane = threadIdx.x & 63, wid = threadIdx.x >> 6;
  const int wm = (wid >> 1) * 64, wn = (wid & 1) * 64;
  const int fr = lane & 15, fq = lane >> 4;
  const int tensor = bn / 768;   // block-uniform (768 = 6 * 128)

  if (tensor < 2) {
    // RoPE pairs (d2, d2+32) live in j-tiles (jp, jp+2) of the same lane
    ushort_t* dstT = qkv + (size_t)tensor * TS;
    const float qs = (tensor == 0) ? QSCALE : 1.0f;
#pragma unroll
    for (int i = 0; i < 4; ++i) {
#pragma unroll
      for (int jp = 0; jp < 2; ++jp) {
        const int col = bn + wn + jp * 16 + fr;
        const int rem = col - tensor * 768;
        const int h = rem >> 6;
        const int d2 = rem & 31;
#pragma unroll
        for (int rr = 0; rr < 4; ++rr) {
          const int row = bm + wm + i * 16 + fq * 4 + rr;
          const int b = row >> 10, n = row & 1023;
          const float2 cs = ((const float2*)tab)[n * 32 + d2];
          const float av = acc[i][jp][rr], bv = acc[i][jp + 2][rr];
          const float o1 = (av * cs.x - bv * cs.y) * qs;
          const float o2 = (bv * cs.x + av * cs.y) * qs;
          ushort_t* dst = dstT + ((size_t)(b * NHEAD + h) * SEQ + n) * HD + d2;
          dst[0]  = f2bf(o1);
          dst[32] = f2bf(o2);
        }
      }
    }
  } else {
    // V: rr spans consecutive n at fixed d -> packed 8B transposed stores
    ushort_t* vt = qkv + 2 * (size_t)TS;
#pragma unroll
    for (int i = 0; i < 4; ++i) {
      const int row0 = bm + wm + i * 16 + fq * 4;
      const int b = row0 >> 10, n0 = row0 & 1023;
#pragma unroll
      for (int j = 0; j < 4; ++j) {
        const int col = bn + wn + j * 16 + fr;
        const int rem = col - 1536;
        const int h = rem >> 6, d = rem & 63;
        u32x2 pk;
        pk[0] = pk2(acc[i][j][0], acc[i][j][1]);
        pk[1] = pk2(acc[i][j][2], acc[i][j][3]);
        *(u32x2*)(vt + ((size_t)(b * NHEAD + h) * HD + d) * SEQ + n0) = pk;
      }
    }
  }
}

// GEMM2: out = oattn @ w_projT^T + bias, fp32 output (128x128 core).
__global__ void __launch_bounds__(256) gemm_proj(const ushort_t* __restrict__ A,
                                                 const ushort_t* __restrict__ Bt,
                                                 const float* __restrict__ bias,
                                                 float* __restrict__ Cout) {
  __shared__ __attribute__((aligned(16))) ushort_t ldsA[3][4096];
  __shared__ __attribute__((aligned(16))) ushort_t ldsB[3][4096];
  f32x4 acc[4][4];
  const int f = blockIdx.x;
  const int xcd = f & 7, r = f >> 3;          // r: 0..47
  const int bm = (xcd * 8 + (r & 7)) * 128;
  const int bn = (r >> 3) * 128;              // 6 bn tiles
  gemm_bt_core(A, Bt, bm, bn, ldsA, ldsB, acc);
  const int lane = threadIdx.x & 63, wid = threadIdx.x >> 6;
  const int wm = (wid >> 1) * 64, wn = (wid & 1) * 64;
  const int fr = lane & 15, fq = lane >> 4;
#pragma unroll
  for (int i = 0; i < 4; ++i) {
#pragma unroll
    for (int j = 0; j < 4; ++j) {
      const int col = bn + wn + j * 16 + fr;
      const float bv = bias[col];
#pragma unroll
      for (int rr = 0; rr < 4; ++rr) {
        const int row = bm + wm + i * 16 + fq * 4 + rr;
        Cout[(size_t)row * CDIM + col] = acc[i][j][rr] + bv;
      }
    }
  }
}

// ---------- flash attention, 32x32x16 MFMA ----------
// K staged in swizzled LDS (dbuf); V^T read DIRECTLY from global (L2-resident:
// per-XCD KV working set ~3 MB < 4 MB L2; V frag = contiguous 16B of VT row).
// V frags loaded into regs at iter top -> QK^T+softmax (~300cy) hides L2 latency.
// P^T C->B transform via v_permlane32_swap_b32 (VALU, no LDS round-trip).
__global__ void __launch_bounds__(256) attn_fused(const ushort_t* __restrict__ Qb,
                                                  const ushort_t* __restrict__ Kb,
                                                  const ushort_t* __restrict__ VTb,
                                                  ushort_t* __restrict__ Ob) {
  __shared__ __attribute__((aligned(16))) ushort_t ldsK[2][4096];  // 512 swizzled 16B slots

  const int tid = threadIdx.x, lane = tid & 63, wid = tid >> 6;
  const int l31 = lane & 31, h = lane >> 5;

  // XCD swizzle: head % 8 == blockIdx % 8
  const int f = blockIdx.x;
  const int xp = f & 7, rest = f >> 3;
  const int g = rest % 12, qb = rest / 12;
  const int head = g * 8 + xp;
  const int q0 = qb * 128;

  const ushort_t* Qh  = Qb  + (size_t)head * (SEQ * HD);
  const ushort_t* Kh  = Kb  + (size_t)head * (SEQ * HD);
  const ushort_t* VTh = VTb + (size_t)head * (HD * SEQ);  // [64][1024]

  // Q B-frags: per dk, B[d=dk*16+8h+j][q=l31] = Q[q][dk*16+8h+j]
  const int qrow = q0 + wid * 32 + l31;
  bf16x8 qF[4];
#pragma unroll
  for (int dk = 0; dk < 4; ++dk)
    qF[dk] = *(const bf16x8*)(Qh + (size_t)qrow * HD + dk * 16 + 8 * h);

  f32x16 ot[2];  // O^T accum per d-tile: col q=l31, row d=dt*32+(reg&3)+8*(reg>>2)+4h
#pragma unroll
  for (int dt = 0; dt < 2; ++dt)
#pragma unroll
    for (int i = 0; i < 16; ++i) ot[dt][i] = 0.f;
  float lsum = 0.f;

  // K staging: slots s = tid, tid+256; r=s>>3 (k-row), c=((s&7)-r)&7 (16B chunk)
  const int s0 = tid, s1 = tid + 256;
  const int r0 = s0 >> 3, c0 = ((s0 & 7) - r0) & 7;
  const int r1 = s1 >> 3, c1 = ((s1 & 7) - r1) & 7;

  // V direct-load bases: lane reads VT[dt*32+l31][kt*64 + kc*16 + 8h .. +8)
  const ushort_t* vBase0 = VTh + (size_t)(l31) * SEQ + 8 * h;        // dt=0
  const ushort_t* vBase1 = VTh + (size_t)(32 + l31) * SEQ + 8 * h;   // dt=1

#define ASTAGE(buf, kt)                                                         \
  {                                                                             \
    async16(Kh + (size_t)((kt) * 64 + r0) * HD + c0 * 8, &ldsK[buf][s0 * 8]);   \
    async16(Kh + (size_t)((kt) * 64 + r1) * HD + c1 * 8, &ldsK[buf][s1 * 8]);   \
  }

  ASTAGE(0, 0);
  __syncthreads();

  for (int kt = 0; kt < 16; ++kt) {
    const int cur = kt & 1;
    if (kt < 15) ASTAGE(cur ^ 1, kt + 1);

    // V frags for this tile: 8 x 16B from L2 (independent of LDS/barrier)
    bf16x8 vf[4][2];
#pragma unroll
    for (int kc = 0; kc < 4; ++kc) {
      vf[kc][0] = *(const bf16x8*)(vBase0 + kt * 64 + kc * 16);
      vf[kc][1] = *(const bf16x8*)(vBase1 + kt * 64 + kc * 16);
    }

    // S^T = K * Q^T : 2 k-subtiles of 32 x 4 d-chunks (K=16 each)
    f32x16 st[2];
    __builtin_amdgcn_s_setprio(1);
#pragma unroll
    for (int ks = 0; ks < 2; ++ks) {
      f32x16 s;
#pragma unroll
      for (int i = 0; i < 16; ++i) s[i] = 0.f;
      const int kr = ks * 32 + l31;          // K row this lane holds (A: m=k)
#pragma unroll
      for (int dk = 0; dk < 4; ++dk) {
        const int sw = (dk * 2 + h + kr) & 7;
        bf16x8 kf = *(const bf16x8*)&ldsK[cur][(kr * 8 + sw) * 8];
        s = MFMA32(kf, qF[dk], s);
      }
      st[ks] = s;
    }
    __builtin_amdgcn_s_setprio(0);

    // exp2 + per-lane partial row-sum + pack into bf16 pairs
    unsigned pk[2][8];
#pragma unroll
    for (int ks = 0; ks < 2; ++ks) {
      float ls = 0.f;
#pragma unroll
      for (int m = 0; m < 8; ++m) {
        const float e0 = __builtin_amdgcn_exp2f(st[ks][2 * m]);
        const float e1 = __builtin_amdgcn_exp2f(st[ks][2 * m + 1]);
        ls += e0 + e1;
        pk[ks][m] = pk2(e0, e1);
      }
      lsum += ls;
    }

    // PV: per k-chunk (K=16): assemble P^T B-frag via permlane32_swap
#pragma unroll
    for (int kc = 0; kc < 4; ++kc) {
      const int ks = kc >> 1, mb = (kc & 1) * 4;
      unsigned w0 = pk[ks][mb + 0], w2 = pk[ks][mb + 2];
      unsigned w1 = pk[ks][mb + 1], w3 = pk[ks][mb + 3];
      plswap(w0, w2);   // w0 = bi[0] (h'=0 source), w2 = bi[2] (h'=1 source)
      plswap(w1, w3);   // w1 = bi[1],               w3 = bi[3]
      u32x4 bi;
      bi[0] = w0; bi[1] = w1; bi[2] = w2; bi[3] = w3;
      const bf16x8 pf = __builtin_bit_cast(bf16x8, bi);
      __builtin_amdgcn_s_setprio(1);
      ot[0] = MFMA32(vf[kc][0], pf, ot[0]);
      ot[1] = MFMA32(vf[kc][1], pf, ot[1]);
      __builtin_amdgcn_s_setprio(0);
    }
    __syncthreads();  // release K buffer; next-tile K DMA issued a whole iter ago
  }
#undef ASTAGE

  // epilogue: combine k-halves of row-sum, normalize, store
  lsum += __shfl_xor(lsum, 32);
  const float inv = 1.0f / lsum;
  const int b = head / NHEAD, hh = head - b * NHEAD;
  ushort_t* obase = Ob + ((size_t)(b * SEQ + qrow)) * CDIM + hh * HD;
#pragma unroll
  for (int dt = 0; dt < 2; ++dt) {
#pragma unroll
    for (int r2 = 0; r2 < 4; ++r2) {
      const int d = dt * 32 + 8 * r2 + 4 * h;
      u32x2 w;
      w[0] = pk2(ot[dt][4 * r2 + 0] * inv, ot[dt][4 * r2 + 1] * inv);
      w[1] = pk2(ot[dt][4 * r2 + 2] * inv, ot[dt][4 * r2 + 3] * inv);
      *(u32x2*)(obase + d) = w;
    }
  }
}

// ---------- launcher ----------
extern "C" void kernel_launch(void* const* d_in, const int* in_sizes, int n_in,
                              void* d_out, int out_size, void* d_ws, size_t ws_size,
                              hipStream_t stream) {
  const float* x      = (const float*)d_in[0];
  const float* w_qkv  = (const float*)d_in[1];
  const float* w_proj = (const float*)d_in[2];
  const float* b_proj = (const float*)d_in[3];
  float* out = (float*)d_out;
  char* ws = (char*)d_ws;

  // ws layout (bytes)
  ushort_t* xb     = (ushort_t*)(ws + 0);          // 8192x768 bf16
  ushort_t* wqkvT  = (ushort_t*)(ws + 12582912);   // 2304x768 bf16
  ushort_t* wprojT = (ushort_t*)(ws + 16121856);   // 768x768 bf16
  ushort_t* qkv    = (ushort_t*)(ws + 17301504);   // q,k (head,n,d) + vt (head,d,n)
  float*    tab    = (float*)  (ws + 55050240);    // 1024x32x2 f32
  ushort_t* oattn  = (ushort_t*)(ws + 55312384);   // 8192x768 bf16

  prep_all<<<5504, 256, 0, stream>>>(x, w_qkv, w_proj, xb, wqkvT, wprojT, tab);
  gemm_qkv<<<1152, 256, 0, stream>>>(xb, wqkvT, tab, qkv);
  attn_fused<<<768, 256, 0, stream>>>(qkv, qkv + TS, qkv + 2 * (size_t)TS, oattn);
  gemm_proj<<<384, 256, 0, stream>>>(oattn, wprojT, b_proj, out);
}

// Round 7
// 194.709 us; speedup vs baseline: 1.0913x; 1.0913x over previous
//
#include <hip/hip_runtime.h>

typedef unsigned short ushort_t;
typedef __bf16 bf16x8 __attribute__((ext_vector_type(8)));
typedef float f32x4 __attribute__((ext_vector_type(4)));
typedef float f32x16 __attribute__((ext_vector_type(16)));
typedef unsigned short u16x8 __attribute__((ext_vector_type(8)));
typedef unsigned int u32x2 __attribute__((ext_vector_type(2)));
typedef unsigned int u32x4 __attribute__((ext_vector_type(4)));

#define MFMA16(a, b, c) __builtin_amdgcn_mfma_f32_16x16x32_bf16((a), (b), (c), 0, 0, 0)
#define MFMA32(a, b, c) __builtin_amdgcn_mfma_f32_32x32x16_bf16((a), (b), (c), 0, 0, 0)

// ---------- constants ----------
// B=8, N=1024, C=768, H=12, hd=64
#define SEQ 1024
#define NHEAD 12
#define HD 64
#define CDIM 768
#define TS 6291456      // per-tensor stride in qkv buf: 96*1024*64
#define QSCALE 0.1803368801111204f   // 0.125 * log2(e)

// ---------- helpers ----------
__device__ __forceinline__ ushort_t f2bf(float f) {
  __bf16 b = (__bf16)f;                       // HW cvt (RNE) on gfx950
  return __builtin_bit_cast(ushort_t, b);
}
__device__ __forceinline__ unsigned pk2(float lo, float hi) {
  return (unsigned)f2bf(lo) | ((unsigned)f2bf(hi) << 16);
}

// permlane32_swap: dst.row1 <-> src.row0. Returns {a.lo|b.lo, a.hi|b.hi}.
__device__ __forceinline__ void plswap(unsigned &a, unsigned &b) {
  u32x2 r = __builtin_amdgcn_permlane32_swap(a, b, false, false);
  a = r[0];
  b = r[1];
}

typedef __attribute__((address_space(1))) void gvoid_t;
typedef __attribute__((address_space(3))) void lvoid_t;
__device__ __forceinline__ void async16(const ushort_t* g, ushort_t* l) {
  __builtin_amdgcn_global_load_lds((gvoid_t*)g, (lvoid_t*)l, 16, 0, 0);
}

// ---------- fused prep: convert x, transpose weights, rope table ----------
__device__ __forceinline__ void transpose_body(const float* __restrict__ in,
                                               ushort_t* __restrict__ out,
                                               int R, int C, int bxi, int byi,
                                               float (*tile)[33]) {
  int bx = bxi * 32, by = byi * 32;
  int tx = threadIdx.x & 31, ty = threadIdx.x >> 5;  // 32 x 8
#pragma unroll
  for (int i = ty; i < 32; i += 8) {
    int r = by + i, c = bx + tx;
    if (r < R && c < C) tile[i][tx] = in[(size_t)r * C + c];
  }
  __syncthreads();
#pragma unroll
  for (int i = ty; i < 32; i += 8) {
    int r = bx + i, c = by + tx;
    if (r < C && c < R) out[(size_t)r * R + c] = f2bf(tile[tx][i]);
  }
}

__global__ void __launch_bounds__(256) prep_all(const float* __restrict__ x,
                                                const float* __restrict__ w_qkv,
                                                const float* __restrict__ w_proj,
                                                ushort_t* __restrict__ xb,
                                                ushort_t* __restrict__ wqkvT,
                                                ushort_t* __restrict__ wprojT,
                                                float* __restrict__ tab) {
  __shared__ float tile[32][33];
  const int bid = blockIdx.x;
  if (bid < 3072) {                       // x fp32 -> bf16
    int i = (bid * 256 + threadIdx.x) * 8;
    float4 a = *(const float4*)(x + i);
    float4 b = *(const float4*)(x + i + 4);
    u16x8 r;
    r[0] = f2bf(a.x); r[1] = f2bf(a.y); r[2] = f2bf(a.z); r[3] = f2bf(a.w);
    r[4] = f2bf(b.x); r[5] = f2bf(b.y); r[6] = f2bf(b.z); r[7] = f2bf(b.w);
    *(u16x8*)(xb + i) = r;
  } else if (bid < 3072 + 1728) {         // w_qkv (768x2304) -> wqkvT (2304x768)
    int t = bid - 3072;
    transpose_body(w_qkv, wqkvT, 768, 2304, t % 72, t / 72, tile);
  } else if (bid < 3072 + 1728 + 576) {   // w_proj (768x768) -> wprojT
    int t = bid - (3072 + 1728);
    transpose_body(w_proj, wprojT, 768, 768, t % 24, t / 24, tile);
  } else {                                // rope cos/sin table (fp64, matches numpy)
    int g = (bid - 5376) * 256 + threadIdx.x;   // 1024*32
    int n = g >> 5, j = g & 31;
    double invf = pow(10000.0, -((double)(2 * j)) / 64.0);
    double fr = (double)n * invf;
    tab[g * 2]     = (float)cos(fr);
    tab[g * 2 + 1] = (float)sin(fr);
  }
}

// ---------- GEMM core: C[128x128] = A[128x768] * Bt[128x768]^T ----------
// 32-wide K steps, TRIPLE-buffered LDS, counted vmcnt; bank-conflict-free
// chunk swizzle applied both-sides (pre-swizzled global src + swizzled read).
__device__ __forceinline__ void gemm_compute32(const ushort_t* la, const ushort_t* lb,
                                               int wm, int wn, int fr, int fq,
                                               f32x4 acc[4][4]) {
  bf16x8 aF[4], bF[4];
#pragma unroll
  for (int i = 0; i < 4; ++i) {
    const int R = wm + i * 16 + fr;
    aF[i] = *(const bf16x8*)(la + R * 32 + (((fq + (R >> 1)) & 3) << 3));
  }
#pragma unroll
  for (int j = 0; j < 4; ++j) {
    const int S = wn + j * 16 + fr;
    bF[j] = *(const bf16x8*)(lb + S * 32 + (((fq + (S >> 1)) & 3) << 3));
  }
#pragma unroll
  for (int i = 0; i < 4; ++i)
#pragma unroll
    for (int j = 0; j < 4; ++j) acc[i][j] = MFMA16(aF[i], bF[j], acc[i][j]);
}

__device__ __forceinline__ void gemm_bt_core(const ushort_t* __restrict__ A,
                                             const ushort_t* __restrict__ Bt,
                                             int bm, int bn,
                                             ushort_t (*ldsA)[4096],
                                             ushort_t (*ldsB)[4096],
                                             f32x4 acc[4][4]) {
  const int tid = threadIdx.x;
  const int lane = tid & 63, wid = tid >> 6;
  const int wm = (wid >> 1) * 64, wn = (wid & 1) * 64;
  const int fr = lane & 15, fq = lane >> 4;
#pragma unroll
  for (int i = 0; i < 4; ++i)
#pragma unroll
    for (int j = 0; j < 4; ++j) acc[i][j] = (f32x4){0.f, 0.f, 0.f, 0.f};

  const int srow = tid >> 2;                                  // 0..63
  const int scol = (((tid & 3) - (srow >> 1)) & 3) << 3;      // swizzled src chunk
  const ushort_t* aSrc = A + (size_t)(bm + srow) * CDIM + scol;
  const ushort_t* bSrc = Bt + (size_t)(bn + srow) * CDIM + scol;

#define STAGE_STEP(buf, s)                                                       \
  {                                                                              \
    async16(aSrc + (s) * 32, ldsA[buf] + tid * 8);                               \
    async16(aSrc + (size_t)64 * CDIM + (s) * 32, ldsA[buf] + 2048 + tid * 8);    \
    async16(bSrc + (s) * 32, ldsB[buf] + tid * 8);                               \
    async16(bSrc + (size_t)64 * CDIM + (s) * 32, ldsB[buf] + 2048 + tid * 8);    \
  }

  STAGE_STEP(0, 0);
  STAGE_STEP(1, 1);
  STAGE_STEP(2, 2);

#pragma unroll 3
  for (int s = 0; s < 21; ++s) {
    const int b = s % 3;
    asm volatile("s_waitcnt vmcnt(8)" ::: "memory");
    __builtin_amdgcn_sched_barrier(0);
    __builtin_amdgcn_s_barrier();
    __builtin_amdgcn_sched_barrier(0);
    gemm_compute32(ldsA[b], ldsB[b], wm, wn, fr, fq, acc);
    __builtin_amdgcn_sched_barrier(0);
    __builtin_amdgcn_s_barrier();
    __builtin_amdgcn_sched_barrier(0);
    STAGE_STEP(b, s + 3);
  }
  asm volatile("s_waitcnt vmcnt(8)" ::: "memory");
  __builtin_amdgcn_sched_barrier(0);
  __builtin_amdgcn_s_barrier();
  __builtin_amdgcn_sched_barrier(0);
  gemm_compute32(ldsA[0], ldsB[0], wm, wn, fr, fq, acc);
  asm volatile("s_waitcnt vmcnt(4)" ::: "memory");
  __builtin_amdgcn_sched_barrier(0);
  __builtin_amdgcn_s_barrier();
  __builtin_amdgcn_sched_barrier(0);
  gemm_compute32(ldsA[1], ldsB[1], wm, wn, fr, fq, acc);
  asm volatile("s_waitcnt vmcnt(0)" ::: "memory");
  __builtin_amdgcn_sched_barrier(0);
  __builtin_amdgcn_s_barrier();
  __builtin_amdgcn_sched_barrier(0);
  gemm_compute32(ldsA[2], ldsB[2], wm, wn, fr, fq, acc);
#undef STAGE_STEP
}

// GEMM1: qkv = x @ w_qkv^T with fused RoPE / V-transpose epilogue. (128^2 core)
__global__ void __launch_bounds__(256) gemm_qkv(const ushort_t* __restrict__ A,
                                                const ushort_t* __restrict__ Bt,
                                                const float* __restrict__ tab,
                                                ushort_t* __restrict__ qkv) {
  __shared__ __attribute__((aligned(16))) ushort_t ldsA[3][4096];
  __shared__ __attribute__((aligned(16))) ushort_t ldsB[3][4096];
  f32x4 acc[4][4];
  const int f = blockIdx.x;
  const int xcd = f & 7, r = f >> 3;          // r: 0..143
  const int bm = (xcd * 8 + (r & 7)) * 128;   // 64 bm tiles, 8 per XCD
  const int bn = (r >> 3) * 128;              // 18 bn tiles
  gemm_bt_core(A, Bt, bm, bn, ldsA, ldsB, acc);
  const int lane = threadIdx.x & 63, wid = threadIdx.x >> 6;
  const int wm = (wid >> 1) * 64, wn = (wid & 1) * 64;
  const int fr = lane & 15, fq = lane >> 4;
  const int tensor = bn / 768;   // block-uniform (768 = 6 * 128)

  if (tensor < 2) {
    // RoPE pairs (d2, d2+32) live in j-tiles (jp, jp+2) of the same lane
    ushort_t* dstT = qkv + (size_t)tensor * TS;
    const float qs = (tensor == 0) ? QSCALE : 1.0f;
#pragma unroll
    for (int i = 0; i < 4; ++i) {
#pragma unroll
      for (int jp = 0; jp < 2; ++jp) {
        const int col = bn + wn + jp * 16 + fr;
        const int rem = col - tensor * 768;
        const int h = rem >> 6;
        const int d2 = rem & 31;
#pragma unroll
        for (int rr = 0; rr < 4; ++rr) {
          const int row = bm + wm + i * 16 + fq * 4 + rr;
          const int b = row >> 10, n = row & 1023;
          const float2 cs = ((const float2*)tab)[n * 32 + d2];
          const float av = acc[i][jp][rr], bv = acc[i][jp + 2][rr];
          const float o1 = (av * cs.x - bv * cs.y) * qs;
          const float o2 = (bv * cs.x + av * cs.y) * qs;
          ushort_t* dst = dstT + ((size_t)(b * NHEAD + h) * SEQ + n) * HD + d2;
          dst[0]  = f2bf(o1);
          dst[32] = f2bf(o2);
        }
      }
    }
  } else {
    // V: rr spans consecutive n at fixed d -> packed 8B transposed stores
    ushort_t* vt = qkv + 2 * (size_t)TS;
#pragma unroll
    for (int i = 0; i < 4; ++i) {
      const int row0 = bm + wm + i * 16 + fq * 4;
      const int b = row0 >> 10, n0 = row0 & 1023;
#pragma unroll
      for (int j = 0; j < 4; ++j) {
        const int col = bn + wn + j * 16 + fr;
        const int rem = col - 1536;
        const int h = rem >> 6, d = rem & 63;
        u32x2 pk;
        pk[0] = pk2(acc[i][j][0], acc[i][j][1]);
        pk[1] = pk2(acc[i][j][2], acc[i][j][3]);
        *(u32x2*)(vt + ((size_t)(b * NHEAD + h) * HD + d) * SEQ + n0) = pk;
      }
    }
  }
}

// GEMM2: out = oattn @ w_projT^T + bias, fp32 output (128x128 core).
__global__ void __launch_bounds__(256) gemm_proj(const ushort_t* __restrict__ A,
                                                 const ushort_t* __restrict__ Bt,
                                                 const float* __restrict__ bias,
                                                 float* __restrict__ Cout) {
  __shared__ __attribute__((aligned(16))) ushort_t ldsA[3][4096];
  __shared__ __attribute__((aligned(16))) ushort_t ldsB[3][4096];
  f32x4 acc[4][4];
  const int f = blockIdx.x;
  const int xcd = f & 7, r = f >> 3;          // r: 0..47
  const int bm = (xcd * 8 + (r & 7)) * 128;
  const int bn = (r >> 3) * 128;              // 6 bn tiles
  gemm_bt_core(A, Bt, bm, bn, ldsA, ldsB, acc);
  const int lane = threadIdx.x & 63, wid = threadIdx.x >> 6;
  const int wm = (wid >> 1) * 64, wn = (wid & 1) * 64;
  const int fr = lane & 15, fq = lane >> 4;
#pragma unroll
  for (int i = 0; i < 4; ++i) {
#pragma unroll
    for (int j = 0; j < 4; ++j) {
      const int col = bn + wn + j * 16 + fr;
      const float bv = bias[col];
#pragma unroll
      for (int rr = 0; rr < 4; ++rr) {
        const int row = bm + wm + i * 16 + fq * 4 + rr;
        Cout[(size_t)row * CDIM + col] = acc[i][j][rr] + bv;
      }
    }
  }
}

// ---------- flash attention, 32x32x16 MFMA, swizzled LDS, LDS-free P ----------
// Wave = 32 q (lane&31); block = 4 waves = 128 q. Iter = 64 keys.
// S^T = K·Q^T via MFMA32 (C: col=q=lane&31, row=k'=(reg&3)+8*(reg>>2)+4h).
// LDS slots swizzled (slot = r*8 + ((c+r)&7)) -> conflict-free frag reads.
// P^T C->B transform via v_permlane32_swap_b32 (VALU, no LDS round-trip).
// Iter body ORDERED for cross-pipe overlap: QK^T(ks0) -> QK^T(ks1) ->
// exp/pack(ks0) -> PV(kc0,1) -> exp/pack(ks1) -> PV(kc2,3): each VALU/trans
// burst sits in the shadow of an independent MFMA cluster.
__global__ void __launch_bounds__(256) attn_fused(const ushort_t* __restrict__ Qb,
                                                  const ushort_t* __restrict__ Kb,
                                                  const ushort_t* __restrict__ VTb,
                                                  ushort_t* __restrict__ Ob) {
  __shared__ __attribute__((aligned(16))) ushort_t ldsK[2][4096];  // 512 swizzled 16B slots
  __shared__ __attribute__((aligned(16))) ushort_t ldsV[2][4096];

  const int tid = threadIdx.x, lane = tid & 63, wid = tid >> 6;
  const int l31 = lane & 31, h = lane >> 5;

  // XCD swizzle: head % 8 == blockIdx % 8
  const int f = blockIdx.x;
  const int xp = f & 7, rest = f >> 3;
  const int g = rest % 12, qb = rest / 12;
  const int head = g * 8 + xp;
  const int q0 = qb * 128;

  const ushort_t* Qh  = Qb  + (size_t)head * (SEQ * HD);
  const ushort_t* Kh  = Kb  + (size_t)head * (SEQ * HD);
  const ushort_t* VTh = VTb + (size_t)head * (HD * SEQ);  // [64][1024]

  // Q B-frags: per dk, B[d=dk*16+8h+j][q=l31] = Q[q][dk*16+8h+j]
  const int qrow = q0 + wid * 32 + l31;
  bf16x8 qF[4];
#pragma unroll
  for (int dk = 0; dk < 4; ++dk)
    qF[dk] = *(const bf16x8*)(Qh + (size_t)qrow * HD + dk * 16 + 8 * h);

  f32x16 ot[2];  // O^T accum per d-tile: col q=l31, row d=dt*32+(reg&3)+8*(reg>>2)+4h
#pragma unroll
  for (int dt = 0; dt < 2; ++dt)
#pragma unroll
    for (int i = 0; i < 16; ++i) ot[dt][i] = 0.f;
  float lsum = 0.f;

  // staging: slots s = tid, tid+256; K: r=s>>3 (k-row), c=((s&7)-r)&7 (16B chunk)
  const int s0 = tid, s1 = tid + 256;
  const int r0 = s0 >> 3, c0 = ((s0 & 7) - r0) & 7;
  const int r1 = s1 >> 3, c1 = ((s1 & 7) - r1) & 7;

#define ASTAGE(buf, kt)                                                         \
  {                                                                             \
    async16(Kh + (size_t)((kt) * 64 + r0) * HD + c0 * 8, &ldsK[buf][s0 * 8]);   \
    async16(Kh + (size_t)((kt) * 64 + r1) * HD + c1 * 8, &ldsK[buf][s1 * 8]);   \
    async16(VTh + (size_t)r0 * SEQ + (kt) * 64 + c0 * 8, &ldsV[buf][s0 * 8]);   \
    async16(VTh + (size_t)r1 * SEQ + (kt) * 64 + c1 * 8, &ldsV[buf][s1 * 8]);   \
  }

  ASTAGE(0, 0);
  __syncthreads();

  for (int kt = 0; kt < 16; ++kt) {
    const int cur = kt & 1;
    if (kt < 15) ASTAGE(cur ^ 1, kt + 1);

    // ---- QK^T both k-subtiles (independent 4-MFMA chains) ----
    f32x16 st[2];
    __builtin_amdgcn_s_setprio(1);
#pragma unroll
    for (int ks = 0; ks < 2; ++ks) {
      f32x16 s;
#pragma unroll
      for (int i = 0; i < 16; ++i) s[i] = 0.f;
      const int kr = ks * 32 + l31;          // K row this lane holds (A: m=k)
#pragma unroll
      for (int dk = 0; dk < 4; ++dk) {
        const int sw = (dk * 2 + h + kr) & 7;
        bf16x8 kf = *(const bf16x8*)&ldsK[cur][(kr * 8 + sw) * 8];
        s = MFMA32(kf, qF[dk], s);
      }
      st[ks] = s;
    }
    __builtin_amdgcn_s_setprio(0);

    // ---- per-half softmax + PV, interleaved so VALU hides under MFMA ----
    unsigned pk[2][8];
#pragma unroll
    for (int ks = 0; ks < 2; ++ks) {
      // exp2 + partial row-sum + pack for this half
      float ls = 0.f;
#pragma unroll
      for (int m = 0; m < 8; ++m) {
        const float e0 = __builtin_amdgcn_exp2f(st[ks][2 * m]);
        const float e1 = __builtin_amdgcn_exp2f(st[ks][2 * m + 1]);
        ls += e0 + e1;
        pk[ks][m] = pk2(e0, e1);
      }
      lsum += ls;

      // PV for this half's two k-chunks (kc = ks*2, ks*2+1)
#pragma unroll
      for (int kcl = 0; kcl < 2; ++kcl) {
        const int kc = ks * 2 + kcl;
        const int mb = kcl * 4;
        unsigned w0 = pk[ks][mb + 0], w2 = pk[ks][mb + 2];
        unsigned w1 = pk[ks][mb + 1], w3 = pk[ks][mb + 3];
        plswap(w0, w2);   // w0 = bi[0] (h'=0 source), w2 = bi[2] (h'=1 source)
        plswap(w1, w3);   // w1 = bi[1],               w3 = bi[3]
        u32x4 bi;
        bi[0] = w0; bi[1] = w1; bi[2] = w2; bi[3] = w3;
        const bf16x8 pf = __builtin_bit_cast(bf16x8, bi);
        __builtin_amdgcn_s_setprio(1);
#pragma unroll
        for (int dt = 0; dt < 2; ++dt) {
          const int dr = dt * 32 + l31;        // V^T row (A: m=d)
          const int sw = (kc * 2 + h + dr) & 7;
          bf16x8 vf = *(const bf16x8*)&ldsV[cur][(dr * 8 + sw) * 8];
          ot[dt] = MFMA32(vf, pf, ot[dt]);
        }
        __builtin_amdgcn_s_setprio(0);
      }
    }
    __syncthreads();  // release buffers; next-tile DMA was issued a whole iter ago
  }
#undef ASTAGE

  // epilogue: combine k-halves of row-sum, normalize, store
  lsum += __shfl_xor(lsum, 32);
  const float inv = 1.0f / lsum;
  const int b = head / NHEAD, hh = head - b * NHEAD;
  ushort_t* obase = Ob + ((size_t)(b * SEQ + qrow)) * CDIM + hh * HD;
#pragma unroll
  for (int dt = 0; dt < 2; ++dt) {
#pragma unroll
    for (int r2 = 0; r2 < 4; ++r2) {
      const int d = dt * 32 + 8 * r2 + 4 * h;
      u32x2 w;
      w[0] = pk2(ot[dt][4 * r2 + 0] * inv, ot[dt][4 * r2 + 1] * inv);
      w[1] = pk2(ot[dt][4 * r2 + 2] * inv, ot[dt][4 * r2 + 3] * inv);
      *(u32x2*)(obase + d) = w;
    }
  }
}

// ---------- launcher ----------
extern "C" void kernel_launch(void* const* d_in, const int* in_sizes, int n_in,
                              void* d_out, int out_size, void* d_ws, size_t ws_size,
                              hipStream_t stream) {
  const float* x      = (const float*)d_in[0];
  const float* w_qkv  = (const float*)d_in[1];
  const float* w_proj = (const float*)d_in[2];
  const float* b_proj = (const float*)d_in[3];
  float* out = (float*)d_out;
  char* ws = (char*)d_ws;

  // ws layout (bytes)
  ushort_t* xb     = (ushort_t*)(ws + 0);          // 8192x768 bf16
  ushort_t* wqkvT  = (ushort_t*)(ws + 12582912);   // 2304x768 bf16
  ushort_t* wprojT = (ushort_t*)(ws + 16121856);   // 768x768 bf16
  ushort_t* qkv    = (ushort_t*)(ws + 17301504);   // q,k (head,n,d) + vt (head,d,n)
  float*    tab    = (float*)  (ws + 55050240);    // 1024x32x2 f32
  ushort_t* oattn  = (ushort_t*)(ws + 55312384);   // 8192x768 bf16

  prep_all<<<5504, 256, 0, stream>>>(x, w_qkv, w_proj, xb, wqkvT, wprojT, tab);
  gemm_qkv<<<1152, 256, 0, stream>>>(xb, wqkvT, tab, qkv);
  attn_fused<<<768, 256, 0, stream>>>(qkv, qkv + TS, qkv + 2 * (size_t)TS, oattn);
  gemm_proj<<<384, 256, 0, stream>>>(oattn, wprojT, b_proj, out);
}